// Round 5
// baseline (1631.475 us; speedup 1.0000x reference)
//
#include <hip/hip_runtime.h>
#include <math.h>

typedef unsigned short ushort_t;
typedef __bf16 bf16x8 __attribute__((ext_vector_type(8)));
typedef float f32x4 __attribute__((ext_vector_type(4)));

#define HEADS 16
#define RES_ELEMS ((size_t)2048 * 1024)

__device__ __forceinline__ ushort_t f2b(float f) {
    unsigned int u = __float_as_uint(f);
    unsigned int r = (u + 0x7FFFu + ((u >> 16) & 1u)) >> 16;
    return (ushort_t)r;
}

__device__ __forceinline__ void g2lds(const void* g, void* l) {
    __builtin_amdgcn_global_load_lds(
        (const __attribute__((address_space(1))) unsigned int*)g,
        (__attribute__((address_space(3))) unsigned int*)l, 16, 0, 0);
}

// ---------------------------------------------------------------- copy x -> residual
__global__ __launch_bounds__(256) void copy_kernel(const float* __restrict__ x,
                                                   float* __restrict__ y) {
    int i = blockIdx.x * 256 + threadIdx.x;
    ((float4*)y)[i] = ((const float4*)x)[i];
}

// ---------------------------------------------------------------- weight transpose+convert
// W fp32 [K,N] -> Wt bf16 [N,K]
__global__ __launch_bounds__(256) void transpose_kernel(const float* __restrict__ W,
                                                        ushort_t* __restrict__ Wt,
                                                        int K, int N) {
    __shared__ ushort_t sT[64 * 72];
    const int t = threadIdx.x;
    const int k0 = blockIdx.y * 64;
    const int n0 = blockIdx.x * 64;
    const int kk = t >> 4;          // 0..15
    const int nc = (t & 15) * 4;    // 0..60
#pragma unroll
    for (int i = 0; i < 4; i++) {
        int k = kk + i * 16;
        float4 v = *(const float4*)(W + (size_t)(k0 + k) * N + n0 + nc);
        const float* vf = (const float*)&v;
#pragma unroll
        for (int j = 0; j < 4; j++) sT[(nc + j) * 72 + k] = f2b(vf[j]);
    }
    __syncthreads();
#pragma unroll
    for (int p = 0; p < 2; p++) {
        int u = t + p * 256;
        int n = u >> 3;
        int kc = (u & 7) * 8;
        *(uint4*)(Wt + (size_t)(n0 + n) * K + k0 + kc) = *(const uint4*)(sT + n * 72 + kc);
    }
}

// ---------------------------------------------------------------- LayerNorm (+ optional split-K fold)
// x (res) fp32 [2048,1024]; part: np fp32 slices folded into res first (written back).
__global__ __launch_bounds__(256) void ln_kernel(float* __restrict__ x,
                                                 const float* __restrict__ part, int np,
                                                 const float* __restrict__ s,
                                                 const float* __restrict__ b,
                                                 ushort_t* __restrict__ out) {
    int row = blockIdx.x;
    int t = threadIdx.x;
    size_t off = (size_t)row * 1024 + t * 4;
    float4 xv = *(const float4*)(x + off);
    for (int p = 0; p < np; p++) {
        float4 pv = *(const float4*)(part + (size_t)p * RES_ELEMS + off);
        xv.x += pv.x; xv.y += pv.y; xv.z += pv.z; xv.w += pv.w;
    }
    if (np > 0) *(float4*)(x + off) = xv;
    float sum = xv.x + xv.y + xv.z + xv.w;
    float sq = xv.x * xv.x + xv.y * xv.y + xv.z * xv.z + xv.w * xv.w;
#pragma unroll
    for (int m = 1; m < 64; m <<= 1) {
        sum += __shfl_xor(sum, m);
        sq += __shfl_xor(sq, m);
    }
    __shared__ float red[8];
    int wave = t >> 6, lane = t & 63;
    if (lane == 0) { red[wave] = sum; red[4 + wave] = sq; }
    __syncthreads();
    sum = red[0] + red[1] + red[2] + red[3];
    sq = red[4] + red[5] + red[6] + red[7];
    float mean = sum * (1.0f / 1024.0f);
    float var = sq * (1.0f / 1024.0f) - mean * mean;
    float inv = rsqrtf(var + 1e-5f);
    float4 sv = *(const float4*)(s + t * 4);
    float4 bv = *(const float4*)(b + t * 4);
    unsigned int lo = (unsigned int)f2b((xv.x - mean) * inv * sv.x + bv.x) |
                      ((unsigned int)f2b((xv.y - mean) * inv * sv.y + bv.y) << 16);
    unsigned int hi = (unsigned int)f2b((xv.z - mean) * inv * sv.z + bv.z) |
                      ((unsigned int)f2b((xv.w - mean) * inv * sv.w + bv.w) << 16);
    uint2 o;
    o.x = lo; o.y = hi;
    *(uint2*)(out + (size_t)row * 1024 + t * 4) = o;
}

// ---------------------------------------------------------------- final split-K fold (last layer)
__global__ __launch_bounds__(256) void reduce_kernel(float* __restrict__ res,
                                                     const float* __restrict__ part, int np) {
    size_t i = ((size_t)blockIdx.x * 256 + threadIdx.x) * 4;
    float4 a = *(const float4*)(res + i);
    for (int p = 0; p < np; p++) {
        float4 pv = *(const float4*)(part + (size_t)p * RES_ELEMS + i);
        a.x += pv.x; a.y += pv.y; a.z += pv.z; a.w += pv.w;
    }
    *(float4*)(res + i) = a;
}

// ---------------------------------------------------------------- GEMM, 64x64 tile, 3-deep pipeline
// A bf16 [M,K] row-major, Bt bf16 [N,K] row-major, staged via global_load_lds with
// XOR-swizzled k-chunks (chunk_phys c holds global chunk c ^ (row&7)).
// Block tile 64 x 64, 4 waves each computing a 32x32 quadrant (2x2 16x16 frags).
// 3 LDS buffers (48 KB -> 3 blocks/CU), counted vmcnt(4) keeps tile kt+1's loads in
// flight across the raw s_barrier; vmcnt(0) only on the final tile. Latency hiding
// comes from 3 INDEPENDENT blocks/CU overlapping (m114 mechanism).
// Split-K over blockIdx.z (Ks = K/gz): slice 0 -> res RMW (single writer), slice 1+
// -> fp32 partial (L3-resident, folded into the next LN). MODE 0/2 use gz=1.
// XCD-chunked blockIdx swizzle (grid divisible by 8) for L2 locality.
// MODE 0: QKV scatter -> q[b,h,n,d], k[b,h,n,d], vt[b,h,d,n] (bf16)
// MODE 1: res[m,n] += C + bias[n] (bz 0) / part = C (bz >= 1)
// MODE 2: outb[m,n] = bf16(gelu(C + bias[n]))
template <int MODE>
__global__ __launch_bounds__(256) void gemm_bt_kernel(
    const ushort_t* __restrict__ A, const ushort_t* __restrict__ Bt,
    const float* __restrict__ bias, float* __restrict__ res,
    float* __restrict__ part,
    ushort_t* __restrict__ outb, ushort_t* __restrict__ qo,
    ushort_t* __restrict__ ko, ushort_t* __restrict__ vto, int K, int N) {
    __shared__ __align__(16) ushort_t sA[3][64 * 64];   // 3 x 8 KB
    __shared__ __align__(16) ushort_t sB[3][64 * 64];   // 3 x 8 KB
    const int t = threadIdx.x;
    const int lane = t & 63;
    const int wave = t >> 6;
    const int l15 = lane & 15;
    const int quad = lane >> 4;
    const int wm = wave >> 1, wn = wave & 1;

    // XCD-chunked swizzle over the full 3D grid (round-robin dispatch).
    const int gx = gridDim.x, gy = gridDim.y, gz = gridDim.z;
    const int nwg = gx * gy * gz;
    const int L = blockIdx.x + gx * (blockIdx.y + gy * blockIdx.z);
    const int f = (L & 7) * (nwg >> 3) + (L >> 3);
    const int bx = f % gx;
    const int rem = f / gx;
    const int by = rem % gy;
    const int bz = rem / gy;

    const int m0 = by * 64;
    const int n0 = bx * 64;
    const int Ks = K / gz;
    const int kbeg = bz * Ks;

    f32x4 acc[2][2];
#pragma unroll
    for (int i = 0; i < 2; i++)
#pragma unroll
        for (int j = 0; j < 2; j++) acc[i][j] = (f32x4){0.f, 0.f, 0.f, 0.f};

    // staging: slot u = p*256 + wave*64 + lane; row = u>>3 = p*32 + wave*8 + (lane>>3);
    // c_phys = lane&7; global chunk = c_phys ^ (row&7) = (lane&7) ^ (lane>>3).
    const int rlow = lane >> 3;
    const int chunk = (lane & 7) ^ rlow;
    const int rowS = wave * 8 + rlow;  // + p*32
    const ushort_t* gA = A + (size_t)(m0 + rowS) * K + kbeg + chunk * 8;
    const ushort_t* gB = Bt + (size_t)(n0 + rowS) * K + kbeg + chunk * 8;
    const int lslot = wave * 512;  // + p*2048 (wave-uniform base; lane offset implicit)
    const int xorv = l15 & 7;

    const int nkt = Ks >> 6;  // >= 8 always
    // prologue: stage tiles 0 and 1 (4 loads/wave each)
#pragma unroll
    for (int b2 = 0; b2 < 2; b2++) {
#pragma unroll
        for (int p = 0; p < 2; p++) {
            g2lds(gA + (size_t)p * 32 * K + b2 * 64, &sA[b2][0] + lslot + p * 2048);
            g2lds(gB + (size_t)p * 32 * K + b2 * 64, &sB[b2][0] + lslot + p * 2048);
        }
    }

    int cur = 0;  // buffer holding tile kt
    for (int kt = 0; kt < nkt; kt++) {
        // wait: tile kt's 4 loads landed; tile kt+1's 4 may remain in flight
        if (kt + 1 < nkt)
            asm volatile("s_waitcnt vmcnt(4)" ::: "memory");
        else
            asm volatile("s_waitcnt vmcnt(0)" ::: "memory");
        __builtin_amdgcn_sched_barrier(0);
        __builtin_amdgcn_s_barrier();
        __builtin_amdgcn_sched_barrier(0);
        if (kt + 2 < nkt) {
            const size_t koff = (size_t)(kt + 2) * 64;
            const int nb = cur >= 1 ? cur - 1 : 2;  // (cur + 2) % 3
            ushort_t* dA = &sA[nb][0] + lslot;
            ushort_t* dB = &sB[nb][0] + lslot;
#pragma unroll
            for (int p = 0; p < 2; p++) {
                g2lds(gA + (size_t)p * 32 * K + koff, dA + p * 2048);
                g2lds(gB + (size_t)p * 32 * K + koff, dB + p * 2048);
            }
        }
        const ushort_t* cA = &sA[cur][0];
        const ushort_t* cB = &sB[cur][0];
#pragma unroll
        for (int ks = 0; ks < 2; ks++) {
            const int co = ((ks * 4 + quad) ^ xorv) * 8;
            bf16x8 af[2], bf[2];
#pragma unroll
            for (int i = 0; i < 2; i++)
                af[i] = *(const bf16x8*)(cA + (wm * 32 + i * 16 + l15) * 64 + co);
#pragma unroll
            for (int i = 0; i < 2; i++)
                bf[i] = *(const bf16x8*)(cB + (wn * 32 + i * 16 + l15) * 64 + co);
#pragma unroll
            for (int mi = 0; mi < 2; mi++)
#pragma unroll
                for (int ni = 0; ni < 2; ni++)
                    acc[mi][ni] = __builtin_amdgcn_mfma_f32_16x16x32_bf16(
                        af[mi], bf[ni], acc[mi][ni], 0, 0, 0);
        }
        __builtin_amdgcn_sched_barrier(0);
        cur = cur == 2 ? 0 : cur + 1;
    }
    // epilogue: C/D layout row = quad*4+r, col = l15
#pragma unroll
    for (int mi = 0; mi < 2; mi++) {
#pragma unroll
        for (int ni = 0; ni < 2; ni++) {
#pragma unroll
            for (int r = 0; r < 4; r++) {
                int mg = m0 + wm * 32 + mi * 16 + quad * 4 + r;
                int ng = n0 + wn * 32 + ni * 16 + l15;
                float c = acc[mi][ni][r];
                if (MODE == 1) {
                    size_t idx = (size_t)mg * N + ng;
                    if (bz == 0)
                        res[idx] = res[idx] + c + bias[ng];
                    else
                        part[(size_t)(bz - 1) * RES_ELEMS + idx] = c;
                } else if (MODE == 2) {
                    float vv = c + bias[ng];
                    float g = 0.5f * vv * (1.0f + erff(vv * 0.70710678118654752f));
                    outb[(size_t)mg * N + ng] = f2b(g);
                } else {
                    int qkv = ng >> 10;
                    int rem2 = ng & 1023;
                    int hh = rem2 >> 6;
                    int dd = rem2 & 63;
                    int bb = mg >> 10;
                    int seq = mg & 1023;
                    ushort_t val = f2b(c);
                    if (qkv == 0)
                        qo[((size_t)(bb * HEADS + hh) * 1024 + seq) * 64 + dd] = val;
                    else if (qkv == 1)
                        ko[((size_t)(bb * HEADS + hh) * 1024 + seq) * 64 + dd] = val;
                    else
                        vto[((size_t)(bb * HEADS + hh) * 64 + dd) * 1024 + seq] = val;
                }
            }
        }
    }
}

// ---------------------------------------------------------------- flash attention
// q,k: [b,h,1024,64] bf16; vt: [b,h,64,1024] bf16; o: [b,1024,1024] bf16
// T14 async-stage: K/V tile kt+1's global loads issue into registers BEFORE the
// barrier, so HBM/L2 latency hides under tile kt's QK/softmax/PV compute; the
// register tile is ds_written at the top of the next iteration.
__global__ __launch_bounds__(256) void attn_kernel(const ushort_t* __restrict__ q,
                                                   const ushort_t* __restrict__ k,
                                                   const ushort_t* __restrict__ vt,
                                                   ushort_t* __restrict__ o) {
    __shared__ __align__(16) ushort_t sK[64 * 72];
    __shared__ __align__(16) ushort_t sV[64 * 72];
    __shared__ __align__(16) ushort_t sP[4 * 16 * 72];
    const int t = threadIdx.x;
    const int lane = t & 63;
    const int w = t >> 6;
    const int l15 = lane & 15;
    const int quad = lane >> 4;
    const int L = blockIdx.x + 16 * blockIdx.y;  // grid (16,32) = 512
    const int f = (L & 7) * 64 + (L >> 3);
    const int qt = f & 15;
    const int bh = f >> 4;

    bf16x8 aq[2];
    const ushort_t* qbase = q + ((size_t)bh * 1024 + qt * 64 + w * 16 + l15) * 64;
    aq[0] = *(const bf16x8*)(qbase + quad * 8);
    aq[1] = *(const bf16x8*)(qbase + 32 + quad * 8);

    float m_old[4], l_sum[4];
    f32x4 oacc[4];
#pragma unroll
    for (int r = 0; r < 4; r++) { m_old[r] = -1e30f; l_sum[r] = 0.f; }
#pragma unroll
    for (int i = 0; i < 4; i++) oacc[i] = (f32x4){0.f, 0.f, 0.f, 0.f};

    const float scale = 0.03125f;  // 1024^-0.5 (reference scales by full D!)

    const int row0 = t >> 3, ch0 = (t & 7) * 8;          // p=0 slot
    const int row1 = (t + 256) >> 3;                      // p=1 slot (same ch)
    uint4 rK[2], rV[2];
#pragma unroll
    for (int p = 0; p < 2; p++) {
        int row = p == 0 ? row0 : row1;
        rK[p] = *(const uint4*)(k + ((size_t)bh * 1024 + row) * 64 + ch0);
        rV[p] = *(const uint4*)(vt + ((size_t)bh * 64 + row) * 1024 + ch0);
    }

    for (int kt = 0; kt < 16; kt++) {
        __syncthreads();  // all waves done reading sK/sV of tile kt-1
#pragma unroll
        for (int p = 0; p < 2; p++) {
            int row = p == 0 ? row0 : row1;
            *(uint4*)(sK + row * 72 + ch0) = rK[p];
            *(uint4*)(sV + row * 72 + ch0) = rV[p];
        }
        if (kt + 1 < 16) {
#pragma unroll
            for (int p = 0; p < 2; p++) {
                int row = p == 0 ? row0 : row1;
                rK[p] = *(const uint4*)(k + ((size_t)bh * 1024 + (kt + 1) * 64 + row) * 64 + ch0);
                rV[p] = *(const uint4*)(vt + ((size_t)bh * 64 + row) * 1024 + (kt + 1) * 64 + ch0);
            }
        }
        __syncthreads();  // ds_writes visible
        f32x4 s[4];
#pragma unroll
        for (int nt = 0; nt < 4; nt++) {
            f32x4 a = (f32x4){0.f, 0.f, 0.f, 0.f};
#pragma unroll
            for (int ks = 0; ks < 2; ks++) {
                bf16x8 bk = *(const bf16x8*)(sK + (nt * 16 + l15) * 72 + ks * 32 + quad * 8);
                a = __builtin_amdgcn_mfma_f32_16x16x32_bf16(aq[ks], bk, a, 0, 0, 0);
            }
            s[nt] = a * scale;
        }
        float alpha[4];
#pragma unroll
        for (int r = 0; r < 4; r++) {
            float mx = fmaxf(fmaxf(s[0][r], s[1][r]), fmaxf(s[2][r], s[3][r]));
#pragma unroll
            for (int msk = 1; msk < 16; msk <<= 1) mx = fmaxf(mx, __shfl_xor(mx, msk));
            float mnew = fmaxf(m_old[r], mx);
            alpha[r] = __expf(m_old[r] - mnew);
            float psum = 0.f;
#pragma unroll
            for (int nt = 0; nt < 4; nt++) {
                float p = __expf(s[nt][r] - mnew);
                s[nt][r] = p;
                psum += p;
            }
#pragma unroll
            for (int msk = 1; msk < 16; msk <<= 1) psum += __shfl_xor(psum, msk);
            l_sum[r] = l_sum[r] * alpha[r] + psum;
            m_old[r] = mnew;
        }
#pragma unroll
        for (int i = 0; i < 4; i++)
#pragma unroll
            for (int r = 0; r < 4; r++) oacc[i][r] *= alpha[r];
#pragma unroll
        for (int nt = 0; nt < 4; nt++)
#pragma unroll
            for (int r = 0; r < 4; r++)
                sP[w * 1152 + (quad * 4 + r) * 72 + nt * 16 + l15] = f2b(s[nt][r]);
        __syncthreads();
#pragma unroll
        for (int nt = 0; nt < 4; nt++) {
#pragma unroll
            for (int ks = 0; ks < 2; ks++) {
                bf16x8 ap = *(const bf16x8*)(sP + w * 1152 + l15 * 72 + ks * 32 + quad * 8);
                bf16x8 bv = *(const bf16x8*)(sV + (nt * 16 + l15) * 72 + ks * 32 + quad * 8);
                oacc[nt] = __builtin_amdgcn_mfma_f32_16x16x32_bf16(ap, bv, oacc[nt], 0, 0, 0);
            }
        }
    }
    int b = bh >> 4, hh = bh & 15;
#pragma unroll
    for (int nt = 0; nt < 4; nt++)
#pragma unroll
        for (int r = 0; r < 4; r++) {
            int row = qt * 64 + w * 16 + quad * 4 + r;
            float val = oacc[nt][r] / l_sum[r];
            o[((size_t)b * 1024 + row) * 1024 + hh * 64 + nt * 16 + l15] = f2b(val);
        }
}

// ---------------------------------------------------------------- launch
// ws map (ws_size ~400 MB; fills show 393 MB):
//   h    @  0 MB (4)   ln out / GEMM A
//   qb   @  4 MB (4), kb @ 8 (4), vtb @ 12 (4), ob @ 16 (4)  — attn phase
//   ub   @  4 MB (16)  mlp mid (overlaps dead q/k/vt/o)
//   wbuf @ 20 MB (8): wqkv_t@20(6) + wo_t@26(2); later w1_t@20(8); later w2_t@20(8)
//   part_wo @ 28 MB (8): w_out split-K partial, folded by ln2
//   part_ml @ 36 MB (8): MLP2 split-K partial, folded by next ln1 / final reduce
extern "C" void kernel_launch(void* const* d_in, const int* in_sizes, int n_in,
                              void* d_out, int out_size, void* d_ws, size_t ws_size,
                              hipStream_t stream) {
    const float* x = (const float*)d_in[0];
    const float* ln1_s = (const float*)d_in[1];
    const float* ln1_b = (const float*)d_in[2];
    const float* w_qkv = (const float*)d_in[3];
    const float* w_out = (const float*)d_in[4];
    const float* b_out = (const float*)d_in[5];
    const float* ln2_s = (const float*)d_in[6];
    const float* ln2_b = (const float*)d_in[7];
    const float* w1 = (const float*)d_in[8];
    const float* b1 = (const float*)d_in[9];
    const float* w2 = (const float*)d_in[10];
    const float* b2 = (const float*)d_in[11];

    float* res = (float*)d_out;
    char* wsb = (char*)d_ws;
    const size_t MB = 1024 * 1024;
    ushort_t* h = (ushort_t*)(wsb + 0 * MB);
    ushort_t* qb = (ushort_t*)(wsb + 4 * MB);
    ushort_t* kb = (ushort_t*)(wsb + 8 * MB);
    ushort_t* vtb = (ushort_t*)(wsb + 12 * MB);
    ushort_t* ob = (ushort_t*)(wsb + 16 * MB);
    ushort_t* ub = (ushort_t*)(wsb + 4 * MB);
    ushort_t* wqkv_t = (ushort_t*)(wsb + 20 * MB);
    ushort_t* wo_t = (ushort_t*)(wsb + 26 * MB);
    ushort_t* w12_t = (ushort_t*)(wsb + 20 * MB);

    int zs = (ws_size >= 44 * MB) ? 2 : 1;
    float* part_wo = (float*)(wsb + 28 * MB);
    float* part_ml = (float*)(wsb + 36 * MB);

    copy_kernel<<<2048, 256, 0, stream>>>(x, res);
    for (int l = 0; l < 6; l++) {
        transpose_kernel<<<dim3(48, 16), 256, 0, stream>>>(
            w_qkv + (size_t)l * 1024 * 3072, wqkv_t, 1024, 3072);
        transpose_kernel<<<dim3(16, 16), 256, 0, stream>>>(
            w_out + (size_t)l * 1024 * 1024, wo_t, 1024, 1024);
        // ln1 folds previous layer's MLP2 partial (layer 0: none)
        ln_kernel<<<2048, 256, 0, stream>>>(res, part_ml, l == 0 ? 0 : zs - 1,
                                            ln1_s + l * 1024, ln1_b + l * 1024, h);
        gemm_bt_kernel<0><<<dim3(48, 32, 1), 256, 0, stream>>>(
            h, wqkv_t, nullptr, nullptr, nullptr, nullptr, qb, kb, vtb, 1024, 3072);
        attn_kernel<<<dim3(16, 32), 256, 0, stream>>>(qb, kb, vtb, ob);
        gemm_bt_kernel<1><<<dim3(16, 32, zs), 256, 0, stream>>>(
            ob, wo_t, b_out + l * 1024, res, part_wo, nullptr, nullptr, nullptr, nullptr,
            1024, 1024);
        transpose_kernel<<<dim3(64, 16), 256, 0, stream>>>(
            w1 + (size_t)l * 1024 * 4096, w12_t, 1024, 4096);
        // ln2 folds w_out partial
        ln_kernel<<<2048, 256, 0, stream>>>(res, part_wo, zs - 1,
                                            ln2_s + l * 1024, ln2_b + l * 1024, h);
        gemm_bt_kernel<2><<<dim3(64, 32, 1), 256, 0, stream>>>(
            h, w12_t, b1 + l * 4096, nullptr, nullptr, ub, nullptr, nullptr, nullptr,
            1024, 4096);
        transpose_kernel<<<dim3(16, 64), 256, 0, stream>>>(
            w2 + (size_t)l * 4096 * 1024, w12_t, 4096, 1024);
        gemm_bt_kernel<1><<<dim3(16, 32, zs), 256, 0, stream>>>(
            ub, w12_t, b2 + l * 1024, res, part_ml, nullptr, nullptr, nullptr, nullptr,
            4096, 1024);
    }
    if (zs > 1) reduce_kernel<<<2048, 256, 0, stream>>>(res, part_ml, zs - 1);
}

// Round 6
// 1478.657 us; speedup vs baseline: 1.1033x; 1.1033x over previous
//
#include <hip/hip_runtime.h>
#include <math.h>

typedef unsigned short ushort_t;
typedef __bf16 bf16x8 __attribute__((ext_vector_type(8)));
typedef float f32x4 __attribute__((ext_vector_type(4)));

#define HEADS 16

__device__ __forceinline__ ushort_t f2b(float f) {
    unsigned int u = __float_as_uint(f);
    unsigned int r = (u + 0x7FFFu + ((u >> 16) & 1u)) >> 16;
    return (ushort_t)r;
}

__device__ __forceinline__ void g2lds(const void* g, void* l) {
    __builtin_amdgcn_global_load_lds(
        (const __attribute__((address_space(1))) unsigned int*)g,
        (__attribute__((address_space(3))) unsigned int*)l, 16, 0, 0);
}

// ---------------------------------------------------------------- copy x -> residual
__global__ __launch_bounds__(256) void copy_kernel(const float* __restrict__ x,
                                                   float* __restrict__ y) {
    int i = blockIdx.x * 256 + threadIdx.x;
    ((float4*)y)[i] = ((const float4*)x)[i];
}

// ---------------------------------------------------------------- weight transpose+convert
// W fp32 [K,N] -> Wt bf16 [N,K]; blockIdx.z batches layers (stride K*N elements each).
__global__ __launch_bounds__(256) void transpose_kernel(const float* __restrict__ W,
                                                        ushort_t* __restrict__ Wt,
                                                        int K, int N) {
    __shared__ ushort_t sT[64 * 72];
    const size_t zoff = (size_t)blockIdx.z * K * N;
    const float* Wz = W + zoff;
    ushort_t* Wtz = Wt + zoff;
    const int t = threadIdx.x;
    const int k0 = blockIdx.y * 64;
    const int n0 = blockIdx.x * 64;
    const int kk = t >> 4;          // 0..15
    const int nc = (t & 15) * 4;    // 0..60
#pragma unroll
    for (int i = 0; i < 4; i++) {
        int k = kk + i * 16;
        float4 v = *(const float4*)(Wz + (size_t)(k0 + k) * N + n0 + nc);
        const float* vf = (const float*)&v;
#pragma unroll
        for (int j = 0; j < 4; j++) sT[(nc + j) * 72 + k] = f2b(vf[j]);
    }
    __syncthreads();
#pragma unroll
    for (int p = 0; p < 2; p++) {
        int u = t + p * 256;
        int n = u >> 3;
        int kc = (u & 7) * 8;
        *(uint4*)(Wtz + (size_t)(n0 + n) * K + k0 + kc) = *(const uint4*)(sT + n * 72 + kc);
    }
}

// ---------------------------------------------------------------- LayerNorm: fp32 res -> bf16 h
__global__ __launch_bounds__(256) void ln_kernel(const float* __restrict__ x,
                                                 const float* __restrict__ s,
                                                 const float* __restrict__ b,
                                                 ushort_t* __restrict__ out) {
    int row = blockIdx.x;
    int t = threadIdx.x;
    const float* xr = x + (size_t)row * 1024;
    float4 xv = *(const float4*)(xr + t * 4);
    float sum = xv.x + xv.y + xv.z + xv.w;
    float sq = xv.x * xv.x + xv.y * xv.y + xv.z * xv.z + xv.w * xv.w;
#pragma unroll
    for (int m = 1; m < 64; m <<= 1) {
        sum += __shfl_xor(sum, m);
        sq += __shfl_xor(sq, m);
    }
    __shared__ float red[8];
    int wave = t >> 6, lane = t & 63;
    if (lane == 0) { red[wave] = sum; red[4 + wave] = sq; }
    __syncthreads();
    sum = red[0] + red[1] + red[2] + red[3];
    sq = red[4] + red[5] + red[6] + red[7];
    float mean = sum * (1.0f / 1024.0f);
    float var = sq * (1.0f / 1024.0f) - mean * mean;
    float inv = rsqrtf(var + 1e-5f);
    float4 sv = *(const float4*)(s + t * 4);
    float4 bv = *(const float4*)(b + t * 4);
    unsigned int lo = (unsigned int)f2b((xv.x - mean) * inv * sv.x + bv.x) |
                      ((unsigned int)f2b((xv.y - mean) * inv * sv.y + bv.y) << 16);
    unsigned int hi = (unsigned int)f2b((xv.z - mean) * inv * sv.z + bv.z) |
                      ((unsigned int)f2b((xv.w - mean) * inv * sv.w + bv.w) << 16);
    uint2 o;
    o.x = lo; o.y = hi;
    *(uint2*)(out + (size_t)row * 1024 + t * 4) = o;
}

// ---------------------------------------------------------------- GEMM, 64x64 tile, 3-deep pipeline
// A bf16 [M,K] row-major, Bt bf16 [N,K] row-major, staged via global_load_lds with
// XOR-swizzled k-chunks (chunk_phys c holds global chunk c ^ (row&7)).
// Block tile 64 x 64, 4 waves each computing a 32x32 quadrant (2x2 16x16 frags).
// 3 LDS buffers (48 KB -> 3 blocks/CU), counted vmcnt(4) keeps tile kt+1's loads in
// flight across the raw s_barrier; vmcnt(0) only on the final tile. Latency hiding
// comes from 3 INDEPENDENT blocks/CU overlapping (m114 mechanism).
// XCD-chunked blockIdx swizzle (grid divisible by 8) for L2 locality.
// MODE 0: QKV scatter -> q[b,h,n,d], k[b,h,n,d], vt[b,h,d,n] (bf16)
// MODE 1: res[m,n] += C + bias[n]   (plain RMW, single writer)
// MODE 2: outb[m,n] = bf16(gelu(C + bias[n]))
template <int MODE>
__global__ __launch_bounds__(256) void gemm_bt_kernel(
    const ushort_t* __restrict__ A, const ushort_t* __restrict__ Bt,
    const float* __restrict__ bias, float* __restrict__ res,
    ushort_t* __restrict__ outb, ushort_t* __restrict__ qo,
    ushort_t* __restrict__ ko, ushort_t* __restrict__ vto, int K, int N) {
    __shared__ __align__(16) ushort_t sA[3][64 * 64];   // 3 x 8 KB
    __shared__ __align__(16) ushort_t sB[3][64 * 64];   // 3 x 8 KB
    const int t = threadIdx.x;
    const int lane = t & 63;
    const int wave = t >> 6;
    const int l15 = lane & 15;
    const int quad = lane >> 4;
    const int wm = wave >> 1, wn = wave & 1;

    // XCD-chunked swizzle: contiguous tile chunks per XCD (round-robin dispatch).
    const int gx = gridDim.x, gy = gridDim.y;
    const int nwg = gx * gy;
    const int L = blockIdx.x + gx * blockIdx.y;
    const int f = (L & 7) * (nwg >> 3) + (L >> 3);
    const int bx = f % gx;
    const int by = f / gx;

    const int m0 = by * 64;
    const int n0 = bx * 64;

    f32x4 acc[2][2];
#pragma unroll
    for (int i = 0; i < 2; i++)
#pragma unroll
        for (int j = 0; j < 2; j++) acc[i][j] = (f32x4){0.f, 0.f, 0.f, 0.f};

    // staging: slot u = p*256 + wave*64 + lane; row = u>>3 = p*32 + wave*8 + (lane>>3);
    // c_phys = lane&7; global chunk = c_phys ^ (row&7) = (lane&7) ^ (lane>>3).
    const int rlow = lane >> 3;
    const int chunk = (lane & 7) ^ rlow;
    const int rowS = wave * 8 + rlow;  // + p*32
    const ushort_t* gA = A + (size_t)(m0 + rowS) * K + chunk * 8;
    const ushort_t* gB = Bt + (size_t)(n0 + rowS) * K + chunk * 8;
    const int lslot = wave * 512;  // + p*2048 (wave-uniform base; lane offset implicit)
    const int xorv = l15 & 7;

    const int nkt = K >> 6;  // >= 16 always
    // prologue: stage tiles 0 and 1 (4 loads/wave each)
#pragma unroll
    for (int b2 = 0; b2 < 2; b2++) {
#pragma unroll
        for (int p = 0; p < 2; p++) {
            g2lds(gA + (size_t)p * 32 * K + b2 * 64, &sA[b2][0] + lslot + p * 2048);
            g2lds(gB + (size_t)p * 32 * K + b2 * 64, &sB[b2][0] + lslot + p * 2048);
        }
    }

    int cur = 0;  // buffer holding tile kt
    for (int kt = 0; kt < nkt; kt++) {
        // wait: tile kt's 4 loads landed; tile kt+1's 4 may remain in flight
        if (kt + 1 < nkt)
            asm volatile("s_waitcnt vmcnt(4)" ::: "memory");
        else
            asm volatile("s_waitcnt vmcnt(0)" ::: "memory");
        __builtin_amdgcn_sched_barrier(0);
        __builtin_amdgcn_s_barrier();
        __builtin_amdgcn_sched_barrier(0);
        if (kt + 2 < nkt) {
            const size_t koff = (size_t)(kt + 2) * 64;
            const int nb = cur >= 1 ? cur - 1 : 2;  // (cur + 2) % 3
            ushort_t* dA = &sA[nb][0] + lslot;
            ushort_t* dB = &sB[nb][0] + lslot;
#pragma unroll
            for (int p = 0; p < 2; p++) {
                g2lds(gA + (size_t)p * 32 * K + koff, dA + p * 2048);
                g2lds(gB + (size_t)p * 32 * K + koff, dB + p * 2048);
            }
        }
        const ushort_t* cA = &sA[cur][0];
        const ushort_t* cB = &sB[cur][0];
#pragma unroll
        for (int ks = 0; ks < 2; ks++) {
            const int co = ((ks * 4 + quad) ^ xorv) * 8;
            bf16x8 af[2], bf[2];
#pragma unroll
            for (int i = 0; i < 2; i++)
                af[i] = *(const bf16x8*)(cA + (wm * 32 + i * 16 + l15) * 64 + co);
#pragma unroll
            for (int i = 0; i < 2; i++)
                bf[i] = *(const bf16x8*)(cB + (wn * 32 + i * 16 + l15) * 64 + co);
#pragma unroll
            for (int mi = 0; mi < 2; mi++)
#pragma unroll
                for (int ni = 0; ni < 2; ni++)
                    acc[mi][ni] = __builtin_amdgcn_mfma_f32_16x16x32_bf16(
                        af[mi], bf[ni], acc[mi][ni], 0, 0, 0);
        }
        __builtin_amdgcn_sched_barrier(0);
        cur = cur == 2 ? 0 : cur + 1;
    }
    // epilogue: C/D layout row = quad*4+r, col = l15
#pragma unroll
    for (int mi = 0; mi < 2; mi++) {
#pragma unroll
        for (int ni = 0; ni < 2; ni++) {
#pragma unroll
            for (int r = 0; r < 4; r++) {
                int mg = m0 + wm * 32 + mi * 16 + quad * 4 + r;
                int ng = n0 + wn * 32 + ni * 16 + l15;
                float c = acc[mi][ni][r];
                if (MODE == 1) {
                    size_t idx = (size_t)mg * N + ng;
                    res[idx] = res[idx] + c + bias[ng];
                } else if (MODE == 2) {
                    float vv = c + bias[ng];
                    float g = 0.5f * vv * (1.0f + erff(vv * 0.70710678118654752f));
                    outb[(size_t)mg * N + ng] = f2b(g);
                } else {
                    int qkv = ng >> 10;
                    int rem = ng & 1023;
                    int hh = rem >> 6;
                    int dd = rem & 63;
                    int bb = mg >> 10;
                    int seq = mg & 1023;
                    ushort_t val = f2b(c);
                    if (qkv == 0)
                        qo[((size_t)(bb * HEADS + hh) * 1024 + seq) * 64 + dd] = val;
                    else if (qkv == 1)
                        ko[((size_t)(bb * HEADS + hh) * 1024 + seq) * 64 + dd] = val;
                    else
                        vto[((size_t)(bb * HEADS + hh) * 64 + dd) * 1024 + seq] = val;
                }
            }
        }
    }
}

// ---------------------------------------------------------------- flash attention
// q,k: [b,h,1024,64] bf16; vt: [b,h,64,1024] bf16; o: [b,1024,1024] bf16 (seq-major, feat=h*64+d)
// XCD-chunked swizzle so each XCD keeps ~4 heads' K/V (1 MB) in its private L2.
__global__ __launch_bounds__(256) void attn_kernel(const ushort_t* __restrict__ q,
                                                   const ushort_t* __restrict__ k,
                                                   const ushort_t* __restrict__ vt,
                                                   ushort_t* __restrict__ o) {
    __shared__ __align__(16) ushort_t sK[64 * 72];
    __shared__ __align__(16) ushort_t sV[64 * 72];
    __shared__ __align__(16) ushort_t sP[4 * 16 * 72];
    const int t = threadIdx.x;
    const int lane = t & 63;
    const int w = t >> 6;
    const int l15 = lane & 15;
    const int quad = lane >> 4;
    const int L = blockIdx.x + 16 * blockIdx.y;  // grid (16,32) = 512
    const int f = (L & 7) * 64 + (L >> 3);
    const int qt = f & 15;
    const int bh = f >> 4;

    bf16x8 aq[2];
    const ushort_t* qbase = q + ((size_t)bh * 1024 + qt * 64 + w * 16 + l15) * 64;
    aq[0] = *(const bf16x8*)(qbase + quad * 8);
    aq[1] = *(const bf16x8*)(qbase + 32 + quad * 8);

    float m_old[4], l_sum[4];
    f32x4 oacc[4];
#pragma unroll
    for (int r = 0; r < 4; r++) { m_old[r] = -1e30f; l_sum[r] = 0.f; }
#pragma unroll
    for (int i = 0; i < 4; i++) oacc[i] = (f32x4){0.f, 0.f, 0.f, 0.f};

    const float scale = 0.03125f;  // 1024^-0.5 (reference scales by full D!)

    for (int kt = 0; kt < 16; kt++) {
        __syncthreads();
#pragma unroll
        for (int p = 0; p < 2; p++) {
            int u = t + p * 256;
            int row = u >> 3, ch = u & 7;
            uint4 v = *(const uint4*)(k + ((size_t)bh * 1024 + kt * 64 + row) * 64 + ch * 8);
            *(uint4*)(sK + row * 72 + ch * 8) = v;
            uint4 v2 = *(const uint4*)(vt + ((size_t)bh * 64 + row) * 1024 + kt * 64 + ch * 8);
            *(uint4*)(sV + row * 72 + ch * 8) = v2;
        }
        __syncthreads();
        f32x4 s[4];
#pragma unroll
        for (int nt = 0; nt < 4; nt++) {
            f32x4 a = (f32x4){0.f, 0.f, 0.f, 0.f};
#pragma unroll
            for (int ks = 0; ks < 2; ks++) {
                bf16x8 bk = *(const bf16x8*)(sK + (nt * 16 + l15) * 72 + ks * 32 + quad * 8);
                a = __builtin_amdgcn_mfma_f32_16x16x32_bf16(aq[ks], bk, a, 0, 0, 0);
            }
            s[nt] = a * scale;
        }
        float alpha[4];
#pragma unroll
        for (int r = 0; r < 4; r++) {
            float mx = fmaxf(fmaxf(s[0][r], s[1][r]), fmaxf(s[2][r], s[3][r]));
#pragma unroll
            for (int msk = 1; msk < 16; msk <<= 1) mx = fmaxf(mx, __shfl_xor(mx, msk));
            float mnew = fmaxf(m_old[r], mx);
            alpha[r] = __expf(m_old[r] - mnew);
            float psum = 0.f;
#pragma unroll
            for (int nt = 0; nt < 4; nt++) {
                float p = __expf(s[nt][r] - mnew);
                s[nt][r] = p;
                psum += p;
            }
#pragma unroll
            for (int msk = 1; msk < 16; msk <<= 1) psum += __shfl_xor(psum, msk);
            l_sum[r] = l_sum[r] * alpha[r] + psum;
            m_old[r] = mnew;
        }
#pragma unroll
        for (int i = 0; i < 4; i++)
#pragma unroll
            for (int r = 0; r < 4; r++) oacc[i][r] *= alpha[r];
#pragma unroll
        for (int nt = 0; nt < 4; nt++)
#pragma unroll
            for (int r = 0; r < 4; r++)
                sP[w * 1152 + (quad * 4 + r) * 72 + nt * 16 + l15] = f2b(s[nt][r]);
        __syncthreads();
#pragma unroll
        for (int nt = 0; nt < 4; nt++) {
#pragma unroll
            for (int ks = 0; ks < 2; ks++) {
                bf16x8 ap = *(const bf16x8*)(sP + w * 1152 + l15 * 72 + ks * 32 + quad * 8);
                bf16x8 bv = *(const bf16x8*)(sV + (nt * 16 + l15) * 72 + ks * 32 + quad * 8);
                oacc[nt] = __builtin_amdgcn_mfma_f32_16x16x32_bf16(ap, bv, oacc[nt], 0, 0, 0);
            }
        }
    }
    int b = bh >> 4, hh = bh & 15;
#pragma unroll
    for (int nt = 0; nt < 4; nt++)
#pragma unroll
        for (int r = 0; r < 4; r++) {
            int row = qt * 64 + w * 16 + quad * 4 + r;
            float val = oacc[nt][r] / l_sum[r];
            o[((size_t)b * 1024 + row) * 1024 + hh * 64 + nt * 16 + l15] = f2b(val);
        }
}

// ---------------------------------------------------------------- launch
// ws map (ws_size ~384 MB per harness fills):
//   h    @  0 MB (4)   ln out / GEMM A
//   qb   @  4 MB (4), kb @ 8 (4), vtb @ 12 (4), ob @ 16 (4)  — attn phase
//   ub   @  4 MB (16)  mlp mid (overlaps dead q/k/vt/o)
// HOIST path (ws >= 170 MB): ALL weights transposed upfront in 4 batched dispatches:
//   wqkv_all @ 24 MB (36 = 6x6), wo_all @ 60 (12), w1_all @ 72 (48), w2_all @ 120 (48)
// FALLBACK (ws < 170 MB): per-layer transposes as before:
//   wqkv_t @ 24 (6), wo_t @ 30 (2), w12_t @ 32 (8, reused for w1 then w2)
extern "C" void kernel_launch(void* const* d_in, const int* in_sizes, int n_in,
                              void* d_out, int out_size, void* d_ws, size_t ws_size,
                              hipStream_t stream) {
    const float* x = (const float*)d_in[0];
    const float* ln1_s = (const float*)d_in[1];
    const float* ln1_b = (const float*)d_in[2];
    const float* w_qkv = (const float*)d_in[3];
    const float* w_out = (const float*)d_in[4];
    const float* b_out = (const float*)d_in[5];
    const float* ln2_s = (const float*)d_in[6];
    const float* ln2_b = (const float*)d_in[7];
    const float* w1 = (const float*)d_in[8];
    const float* b1 = (const float*)d_in[9];
    const float* w2 = (const float*)d_in[10];
    const float* b2 = (const float*)d_in[11];

    float* res = (float*)d_out;
    char* wsb = (char*)d_ws;
    const size_t MB = 1024 * 1024;
    ushort_t* h = (ushort_t*)(wsb + 0 * MB);
    ushort_t* qb = (ushort_t*)(wsb + 4 * MB);
    ushort_t* kb = (ushort_t*)(wsb + 8 * MB);
    ushort_t* vtb = (ushort_t*)(wsb + 12 * MB);
    ushort_t* ob = (ushort_t*)(wsb + 16 * MB);
    ushort_t* ub = (ushort_t*)(wsb + 4 * MB);

    const bool hoist = ws_size >= 170 * MB;
    ushort_t* wqkv_all = (ushort_t*)(wsb + 24 * MB);   // 6 MB/layer
    ushort_t* wo_all = (ushort_t*)(wsb + 60 * MB);     // 2 MB/layer
    ushort_t* w1_all = (ushort_t*)(wsb + 72 * MB);     // 8 MB/layer
    ushort_t* w2_all = (ushort_t*)(wsb + 120 * MB);    // 8 MB/layer
    ushort_t* wqkv_1 = (ushort_t*)(wsb + 24 * MB);     // fallback per-layer
    ushort_t* wo_1 = (ushort_t*)(wsb + 30 * MB);
    ushort_t* w12_1 = (ushort_t*)(wsb + 32 * MB);

    copy_kernel<<<2048, 256, 0, stream>>>(x, res);
    if (hoist) {
        transpose_kernel<<<dim3(48, 16, 6), 256, 0, stream>>>(w_qkv, wqkv_all, 1024, 3072);
        transpose_kernel<<<dim3(16, 16, 6), 256, 0, stream>>>(w_out, wo_all, 1024, 1024);
        transpose_kernel<<<dim3(64, 16, 6), 256, 0, stream>>>(w1, w1_all, 1024, 4096);
        transpose_kernel<<<dim3(16, 64, 6), 256, 0, stream>>>(w2, w2_all, 4096, 1024);
    }
    for (int l = 0; l < 6; l++) {
        ushort_t *wqkv_t, *wo_t, *w1_t, *w2_t;
        if (hoist) {
            wqkv_t = wqkv_all + (size_t)l * 1024 * 3072;
            wo_t = wo_all + (size_t)l * 1024 * 1024;
            w1_t = w1_all + (size_t)l * 1024 * 4096;
            w2_t = w2_all + (size_t)l * 4096 * 1024;
        } else {
            wqkv_t = wqkv_1; wo_t = wo_1; w1_t = w12_1; w2_t = w12_1;
            transpose_kernel<<<dim3(48, 16, 1), 256, 0, stream>>>(
                w_qkv + (size_t)l * 1024 * 3072, wqkv_t, 1024, 3072);
            transpose_kernel<<<dim3(16, 16, 1), 256, 0, stream>>>(
                w_out + (size_t)l * 1024 * 1024, wo_t, 1024, 1024);
        }
        ln_kernel<<<2048, 256, 0, stream>>>(res, ln1_s + l * 1024, ln1_b + l * 1024, h);
        gemm_bt_kernel<0><<<dim3(48, 32), 256, 0, stream>>>(
            h, wqkv_t, nullptr, nullptr, nullptr, qb, kb, vtb, 1024, 3072);
        attn_kernel<<<dim3(16, 32), 256, 0, stream>>>(qb, kb, vtb, ob);
        gemm_bt_kernel<1><<<dim3(16, 32), 256, 0, stream>>>(
            ob, wo_t, b_out + l * 1024, res, nullptr, nullptr, nullptr, nullptr,
            1024, 1024);
        if (!hoist)
            transpose_kernel<<<dim3(64, 16, 1), 256, 0, stream>>>(
                w1 + (size_t)l * 1024 * 4096, w1_t, 1024, 4096);
        ln_kernel<<<2048, 256, 0, stream>>>(res, ln2_s + l * 1024, ln2_b + l * 1024, h);
        gemm_bt_kernel<2><<<dim3(64, 32), 256, 0, stream>>>(
            h, w1_t, b1 + l * 4096, nullptr, ub, nullptr, nullptr, nullptr,
            1024, 4096);
        if (!hoist)
            transpose_kernel<<<dim3(16, 64, 1), 256, 0, stream>>>(
                w2 + (size_t)l * 4096 * 1024, w2_t, 4096, 1024);
        gemm_bt_kernel<1><<<dim3(16, 32), 256, 0, stream>>>(
            ub, w2_t, b2 + l * 1024, res, nullptr, nullptr, nullptr, nullptr,
            4096, 1024);
    }
}

// Round 7
// 1396.358 us; speedup vs baseline: 1.1684x; 1.0589x over previous
//
#include <hip/hip_runtime.h>
#include <math.h>

typedef unsigned short ushort_t;
typedef __bf16 bf16x8 __attribute__((ext_vector_type(8)));
typedef float f32x4 __attribute__((ext_vector_type(4)));

#define HEADS 16

__device__ __forceinline__ ushort_t f2b(float f) {
    unsigned int u = __float_as_uint(f);
    unsigned int r = (u + 0x7FFFu + ((u >> 16) & 1u)) >> 16;
    return (ushort_t)r;
}

__device__ __forceinline__ void g2lds(const void* g, void* l) {
    __builtin_amdgcn_global_load_lds(
        (const __attribute__((address_space(1))) unsigned int*)g,
        (__attribute__((address_space(3))) unsigned int*)l, 16, 0, 0);
}

// ---------------------------------------------------------------- copy x -> residual
__global__ __launch_bounds__(256) void copy_kernel(const float* __restrict__ x,
                                                   float* __restrict__ y) {
    int i = blockIdx.x * 256 + threadIdx.x;
    ((float4*)y)[i] = ((const float4*)x)[i];
}

// ---------------------------------------------------------------- weight transpose+convert
// W fp32 [K,N] -> Wt bf16 [N,K]; blockIdx.z batches layers (stride K*N elements each).
__global__ __launch_bounds__(256) void transpose_kernel(const float* __restrict__ W,
                                                        ushort_t* __restrict__ Wt,
                                                        int K, int N) {
    __shared__ ushort_t sT[64 * 72];
    const size_t zoff = (size_t)blockIdx.z * K * N;
    const float* Wz = W + zoff;
    ushort_t* Wtz = Wt + zoff;
    const int t = threadIdx.x;
    const int k0 = blockIdx.y * 64;
    const int n0 = blockIdx.x * 64;
    const int kk = t >> 4;          // 0..15
    const int nc = (t & 15) * 4;    // 0..60
#pragma unroll
    for (int i = 0; i < 4; i++) {
        int k = kk + i * 16;
        float4 v = *(const float4*)(Wz + (size_t)(k0 + k) * N + n0 + nc);
        const float* vf = (const float*)&v;
#pragma unroll
        for (int j = 0; j < 4; j++) sT[(nc + j) * 72 + k] = f2b(vf[j]);
    }
    __syncthreads();
#pragma unroll
    for (int p = 0; p < 2; p++) {
        int u = t + p * 256;
        int n = u >> 3;
        int kc = (u & 7) * 8;
        *(uint4*)(Wtz + (size_t)(n0 + n) * K + k0 + kc) = *(const uint4*)(sT + n * 72 + kc);
    }
}

// ---------------------------------------------------------------- LayerNorm: fp32 res -> bf16 h
__global__ __launch_bounds__(256) void ln_kernel(const float* __restrict__ x,
                                                 const float* __restrict__ s,
                                                 const float* __restrict__ b,
                                                 ushort_t* __restrict__ out) {
    int row = blockIdx.x;
    int t = threadIdx.x;
    const float* xr = x + (size_t)row * 1024;
    float4 xv = *(const float4*)(xr + t * 4);
    float sum = xv.x + xv.y + xv.z + xv.w;
    float sq = xv.x * xv.x + xv.y * xv.y + xv.z * xv.z + xv.w * xv.w;
#pragma unroll
    for (int m = 1; m < 64; m <<= 1) {
        sum += __shfl_xor(sum, m);
        sq += __shfl_xor(sq, m);
    }
    __shared__ float red[8];
    int wave = t >> 6, lane = t & 63;
    if (lane == 0) { red[wave] = sum; red[4 + wave] = sq; }
    __syncthreads();
    sum = red[0] + red[1] + red[2] + red[3];
    sq = red[4] + red[5] + red[6] + red[7];
    float mean = sum * (1.0f / 1024.0f);
    float var = sq * (1.0f / 1024.0f) - mean * mean;
    float inv = rsqrtf(var + 1e-5f);
    float4 sv = *(const float4*)(s + t * 4);
    float4 bv = *(const float4*)(b + t * 4);
    unsigned int lo = (unsigned int)f2b((xv.x - mean) * inv * sv.x + bv.x) |
                      ((unsigned int)f2b((xv.y - mean) * inv * sv.y + bv.y) << 16);
    unsigned int hi = (unsigned int)f2b((xv.z - mean) * inv * sv.z + bv.z) |
                      ((unsigned int)f2b((xv.w - mean) * inv * sv.w + bv.w) << 16);
    uint2 o;
    o.x = lo; o.y = hi;
    *(uint2*)(out + (size_t)row * 1024 + t * 4) = o;
}

// ---------------------------------------------------------------- GEMM, 64x64 tile, DEPTH-deep pipeline
// A bf16 [M,K] row-major, Bt bf16 [N,K] row-major, staged via global_load_lds with
// XOR-swizzled k-chunks (chunk_phys c holds global chunk c ^ (row&7)).
// Block tile 64 x 64, 4 waves each computing a 32x32 quadrant (2x2 16x16 frags).
// DEPTH=2: 32 KB LDS -> 5 blocks/CU (for grids >= 1280: QKV, MLP1) — max block-level
//          TLP; per-tile drain hidden by 4 other independent blocks (m114 mechanism).
// DEPTH=3: 48 KB LDS, counted vmcnt(4) keeps next tile's loads in flight across the
//          barrier (for grid-capped w_out/MLP2 at 2 blocks/CU).
// setprio(1) around the compute cluster (T5): independent co-resident blocks sit at
// different pipeline phases, so the SIMD scheduler can favor compute-phase waves.
// XCD-chunked blockIdx swizzle (grid divisible by 8) for L2 locality.
// MODE 0: QKV scatter -> q[b,h,n,d], k[b,h,n,d], vt[b,h,d,n] (bf16)
// MODE 1: res[m,n] += C + bias[n]   (plain RMW, single writer)
// MODE 2: outb[m,n] = bf16(gelu(C + bias[n]))
template <int MODE, int DEPTH>
__global__ __launch_bounds__(256) void gemm_bt_kernel(
    const ushort_t* __restrict__ A, const ushort_t* __restrict__ Bt,
    const float* __restrict__ bias, float* __restrict__ res,
    ushort_t* __restrict__ outb, ushort_t* __restrict__ qo,
    ushort_t* __restrict__ ko, ushort_t* __restrict__ vto, int K, int N) {
    __shared__ __align__(16) ushort_t sA[DEPTH][64 * 64];   // DEPTH x 8 KB
    __shared__ __align__(16) ushort_t sB[DEPTH][64 * 64];   // DEPTH x 8 KB
    const int t = threadIdx.x;
    const int lane = t & 63;
    const int wave = t >> 6;
    const int l15 = lane & 15;
    const int quad = lane >> 4;
    const int wm = wave >> 1, wn = wave & 1;

    // XCD-chunked swizzle: contiguous tile chunks per XCD (round-robin dispatch).
    const int gx = gridDim.x, gy = gridDim.y;
    const int nwg = gx * gy;
    const int L = blockIdx.x + gx * blockIdx.y;
    const int f = (L & 7) * (nwg >> 3) + (L >> 3);
    const int bx = f % gx;
    const int by = f / gx;

    const int m0 = by * 64;
    const int n0 = bx * 64;

    f32x4 acc[2][2];
#pragma unroll
    for (int i = 0; i < 2; i++)
#pragma unroll
        for (int j = 0; j < 2; j++) acc[i][j] = (f32x4){0.f, 0.f, 0.f, 0.f};

    // staging: slot u = p*256 + wave*64 + lane; row = u>>3 = p*32 + wave*8 + (lane>>3);
    // c_phys = lane&7; global chunk = c_phys ^ (row&7) = (lane&7) ^ (lane>>3).
    const int rlow = lane >> 3;
    const int chunk = (lane & 7) ^ rlow;
    const int rowS = wave * 8 + rlow;  // + p*32
    const ushort_t* gA = A + (size_t)(m0 + rowS) * K + chunk * 8;
    const ushort_t* gB = Bt + (size_t)(n0 + rowS) * K + chunk * 8;
    const int lslot = wave * 512;  // + p*2048 (wave-uniform base; lane offset implicit)
    const int xorv = l15 & 7;

    const int nkt = K >> 6;  // >= 16 always
    // prologue: stage tiles 0 .. DEPTH-2
#pragma unroll
    for (int b2 = 0; b2 < DEPTH - 1; b2++) {
#pragma unroll
        for (int p = 0; p < 2; p++) {
            g2lds(gA + (size_t)p * 32 * K + b2 * 64, &sA[b2][0] + lslot + p * 2048);
            g2lds(gB + (size_t)p * 32 * K + b2 * 64, &sB[b2][0] + lslot + p * 2048);
        }
    }

    int cur = 0;  // buffer holding tile kt
    for (int kt = 0; kt < nkt; kt++) {
        // wait for tile kt's 4 loads; with DEPTH=3, tile kt+1's 4 stay in flight
        if (DEPTH == 3 && kt + 1 < nkt)
            asm volatile("s_waitcnt vmcnt(4)" ::: "memory");
        else
            asm volatile("s_waitcnt vmcnt(0)" ::: "memory");
        __builtin_amdgcn_sched_barrier(0);
        __builtin_amdgcn_s_barrier();
        __builtin_amdgcn_sched_barrier(0);
        if (kt + DEPTH - 1 < nkt) {
            const size_t koff = (size_t)(kt + DEPTH - 1) * 64;
            int nb = cur + DEPTH - 1;
            if (nb >= DEPTH) nb -= DEPTH;
            ushort_t* dA = &sA[nb][0] + lslot;
            ushort_t* dB = &sB[nb][0] + lslot;
#pragma unroll
            for (int p = 0; p < 2; p++) {
                g2lds(gA + (size_t)p * 32 * K + koff, dA + p * 2048);
                g2lds(gB + (size_t)p * 32 * K + koff, dB + p * 2048);
            }
        }
        const ushort_t* cA = &sA[cur][0];
        const ushort_t* cB = &sB[cur][0];
        __builtin_amdgcn_s_setprio(1);
#pragma unroll
        for (int ks = 0; ks < 2; ks++) {
            const int co = ((ks * 4 + quad) ^ xorv) * 8;
            bf16x8 af[2], bf[2];
#pragma unroll
            for (int i = 0; i < 2; i++)
                af[i] = *(const bf16x8*)(cA + (wm * 32 + i * 16 + l15) * 64 + co);
#pragma unroll
            for (int i = 0; i < 2; i++)
                bf[i] = *(const bf16x8*)(cB + (wn * 32 + i * 16 + l15) * 64 + co);
#pragma unroll
            for (int mi = 0; mi < 2; mi++)
#pragma unroll
                for (int ni = 0; ni < 2; ni++)
                    acc[mi][ni] = __builtin_amdgcn_mfma_f32_16x16x32_bf16(
                        af[mi], bf[ni], acc[mi][ni], 0, 0, 0);
        }
        __builtin_amdgcn_s_setprio(0);
        cur = cur == DEPTH - 1 ? 0 : cur + 1;
    }
    // epilogue: C/D layout row = quad*4+r, col = l15
#pragma unroll
    for (int mi = 0; mi < 2; mi++) {
#pragma unroll
        for (int ni = 0; ni < 2; ni++) {
#pragma unroll
            for (int r = 0; r < 4; r++) {
                int mg = m0 + wm * 32 + mi * 16 + quad * 4 + r;
                int ng = n0 + wn * 32 + ni * 16 + l15;
                float c = acc[mi][ni][r];
                if (MODE == 1) {
                    size_t idx = (size_t)mg * N + ng;
                    res[idx] = res[idx] + c + bias[ng];
                } else if (MODE == 2) {
                    float vv = c + bias[ng];
                    float g = 0.5f * vv * (1.0f + erff(vv * 0.70710678118654752f));
                    outb[(size_t)mg * N + ng] = f2b(g);
                } else {
                    int qkv = ng >> 10;
                    int rem = ng & 1023;
                    int hh = rem >> 6;
                    int dd = rem & 63;
                    int bb = mg >> 10;
                    int seq = mg & 1023;
                    ushort_t val = f2b(c);
                    if (qkv == 0)
                        qo[((size_t)(bb * HEADS + hh) * 1024 + seq) * 64 + dd] = val;
                    else if (qkv == 1)
                        ko[((size_t)(bb * HEADS + hh) * 1024 + seq) * 64 + dd] = val;
                    else
                        vto[((size_t)(bb * HEADS + hh) * 64 + dd) * 1024 + seq] = val;
                }
            }
        }
    }
}

// ---------------------------------------------------------------- flash attention
// q,k: [b,h,1024,64] bf16; vt: [b,h,64,1024] bf16; o: [b,1024,1024] bf16 (seq-major, feat=h*64+d)
// XCD-chunked swizzle so each XCD keeps ~4 heads' K/V (1 MB) in its private L2.
// setprio around the MFMA clusters (T5 — measured +4-7% on independent-block attn).
__global__ __launch_bounds__(256) void attn_kernel(const ushort_t* __restrict__ q,
                                                   const ushort_t* __restrict__ k,
                                                   const ushort_t* __restrict__ vt,
                                                   ushort_t* __restrict__ o) {
    __shared__ __align__(16) ushort_t sK[64 * 72];
    __shared__ __align__(16) ushort_t sV[64 * 72];
    __shared__ __align__(16) ushort_t sP[4 * 16 * 72];
    const int t = threadIdx.x;
    const int lane = t & 63;
    const int w = t >> 6;
    const int l15 = lane & 15;
    const int quad = lane >> 4;
    const int L = blockIdx.x + 16 * blockIdx.y;  // grid (16,32) = 512
    const int f = (L & 7) * 64 + (L >> 3);
    const int qt = f & 15;
    const int bh = f >> 4;

    bf16x8 aq[2];
    const ushort_t* qbase = q + ((size_t)bh * 1024 + qt * 64 + w * 16 + l15) * 64;
    aq[0] = *(const bf16x8*)(qbase + quad * 8);
    aq[1] = *(const bf16x8*)(qbase + 32 + quad * 8);

    float m_old[4], l_sum[4];
    f32x4 oacc[4];
#pragma unroll
    for (int r = 0; r < 4; r++) { m_old[r] = -1e30f; l_sum[r] = 0.f; }
#pragma unroll
    for (int i = 0; i < 4; i++) oacc[i] = (f32x4){0.f, 0.f, 0.f, 0.f};

    const float scale = 0.03125f;  // 1024^-0.5 (reference scales by full D!)

    for (int kt = 0; kt < 16; kt++) {
        __syncthreads();
#pragma unroll
        for (int p = 0; p < 2; p++) {
            int u = t + p * 256;
            int row = u >> 3, ch = u & 7;
            uint4 v = *(const uint4*)(k + ((size_t)bh * 1024 + kt * 64 + row) * 64 + ch * 8);
            *(uint4*)(sK + row * 72 + ch * 8) = v;
            uint4 v2 = *(const uint4*)(vt + ((size_t)bh * 64 + row) * 1024 + kt * 64 + ch * 8);
            *(uint4*)(sV + row * 72 + ch * 8) = v2;
        }
        __syncthreads();
        f32x4 s[4];
        __builtin_amdgcn_s_setprio(1);
#pragma unroll
        for (int nt = 0; nt < 4; nt++) {
            f32x4 a = (f32x4){0.f, 0.f, 0.f, 0.f};
#pragma unroll
            for (int ks = 0; ks < 2; ks++) {
                bf16x8 bk = *(const bf16x8*)(sK + (nt * 16 + l15) * 72 + ks * 32 + quad * 8);
                a = __builtin_amdgcn_mfma_f32_16x16x32_bf16(aq[ks], bk, a, 0, 0, 0);
            }
            s[nt] = a * scale;
        }
        __builtin_amdgcn_s_setprio(0);
        float alpha[4];
#pragma unroll
        for (int r = 0; r < 4; r++) {
            float mx = fmaxf(fmaxf(s[0][r], s[1][r]), fmaxf(s[2][r], s[3][r]));
#pragma unroll
            for (int msk = 1; msk < 16; msk <<= 1) mx = fmaxf(mx, __shfl_xor(mx, msk));
            float mnew = fmaxf(m_old[r], mx);
            alpha[r] = __expf(m_old[r] - mnew);
            float psum = 0.f;
#pragma unroll
            for (int nt = 0; nt < 4; nt++) {
                float p = __expf(s[nt][r] - mnew);
                s[nt][r] = p;
                psum += p;
            }
#pragma unroll
            for (int msk = 1; msk < 16; msk <<= 1) psum += __shfl_xor(psum, msk);
            l_sum[r] = l_sum[r] * alpha[r] + psum;
            m_old[r] = mnew;
        }
#pragma unroll
        for (int i = 0; i < 4; i++)
#pragma unroll
            for (int r = 0; r < 4; r++) oacc[i][r] *= alpha[r];
#pragma unroll
        for (int nt = 0; nt < 4; nt++)
#pragma unroll
            for (int r = 0; r < 4; r++)
                sP[w * 1152 + (quad * 4 + r) * 72 + nt * 16 + l15] = f2b(s[nt][r]);
        __syncthreads();
        __builtin_amdgcn_s_setprio(1);
#pragma unroll
        for (int nt = 0; nt < 4; nt++) {
#pragma unroll
            for (int ks = 0; ks < 2; ks++) {
                bf16x8 ap = *(const bf16x8*)(sP + w * 1152 + l15 * 72 + ks * 32 + quad * 8);
                bf16x8 bv = *(const bf16x8*)(sV + (nt * 16 + l15) * 72 + ks * 32 + quad * 8);
                oacc[nt] = __builtin_amdgcn_mfma_f32_16x16x32_bf16(ap, bv, oacc[nt], 0, 0, 0);
            }
        }
        __builtin_amdgcn_s_setprio(0);
    }
    int b = bh >> 4, hh = bh & 15;
#pragma unroll
    for (int nt = 0; nt < 4; nt++)
#pragma unroll
        for (int r = 0; r < 4; r++) {
            int row = qt * 64 + w * 16 + quad * 4 + r;
            float val = oacc[nt][r] / l_sum[r];
            o[((size_t)b * 1024 + row) * 1024 + hh * 64 + nt * 16 + l15] = f2b(val);
        }
}

// ---------------------------------------------------------------- launch
// ws map (ws_size ~384 MB per harness fills):
//   h    @  0 MB (4)   ln out / GEMM A
//   qb   @  4 MB (4), kb @ 8 (4), vtb @ 12 (4), ob @ 16 (4)  — attn phase
//   ub   @  4 MB (16)  mlp mid (overlaps dead q/k/vt/o)
// HOIST path (ws >= 170 MB): ALL weights transposed upfront in 4 batched dispatches:
//   wqkv_all @ 24 MB (36 = 6x6), wo_all @ 60 (12), w1_all @ 72 (48), w2_all @ 120 (48)
// FALLBACK (ws < 170 MB): per-layer transposes:
//   wqkv_t @ 24 (6), wo_t @ 30 (2), w12_t @ 32 (8, reused for w1 then w2)
extern "C" void kernel_launch(void* const* d_in, const int* in_sizes, int n_in,
                              void* d_out, int out_size, void* d_ws, size_t ws_size,
                              hipStream_t stream) {
    const float* x = (const float*)d_in[0];
    const float* ln1_s = (const float*)d_in[1];
    const float* ln1_b = (const float*)d_in[2];
    const float* w_qkv = (const float*)d_in[3];
    const float* w_out = (const float*)d_in[4];
    const float* b_out = (const float*)d_in[5];
    const float* ln2_s = (const float*)d_in[6];
    const float* ln2_b = (const float*)d_in[7];
    const float* w1 = (const float*)d_in[8];
    const float* b1 = (const float*)d_in[9];
    const float* w2 = (const float*)d_in[10];
    const float* b2 = (const float*)d_in[11];

    float* res = (float*)d_out;
    char* wsb = (char*)d_ws;
    const size_t MB = 1024 * 1024;
    ushort_t* h = (ushort_t*)(wsb + 0 * MB);
    ushort_t* qb = (ushort_t*)(wsb + 4 * MB);
    ushort_t* kb = (ushort_t*)(wsb + 8 * MB);
    ushort_t* vtb = (ushort_t*)(wsb + 12 * MB);
    ushort_t* ob = (ushort_t*)(wsb + 16 * MB);
    ushort_t* ub = (ushort_t*)(wsb + 4 * MB);

    const bool hoist = ws_size >= 170 * MB;
    ushort_t* wqkv_all = (ushort_t*)(wsb + 24 * MB);   // 6 MB/layer
    ushort_t* wo_all = (ushort_t*)(wsb + 60 * MB);     // 2 MB/layer
    ushort_t* w1_all = (ushort_t*)(wsb + 72 * MB);     // 8 MB/layer
    ushort_t* w2_all = (ushort_t*)(wsb + 120 * MB);    // 8 MB/layer
    ushort_t* wqkv_1 = (ushort_t*)(wsb + 24 * MB);     // fallback per-layer
    ushort_t* wo_1 = (ushort_t*)(wsb + 30 * MB);
    ushort_t* w12_1 = (ushort_t*)(wsb + 32 * MB);

    copy_kernel<<<2048, 256, 0, stream>>>(x, res);
    if (hoist) {
        transpose_kernel<<<dim3(48, 16, 6), 256, 0, stream>>>(w_qkv, wqkv_all, 1024, 3072);
        transpose_kernel<<<dim3(16, 16, 6), 256, 0, stream>>>(w_out, wo_all, 1024, 1024);
        transpose_kernel<<<dim3(64, 16, 6), 256, 0, stream>>>(w1, w1_all, 1024, 4096);
        transpose_kernel<<<dim3(16, 64, 6), 256, 0, stream>>>(w2, w2_all, 4096, 1024);
    }
    for (int l = 0; l < 6; l++) {
        ushort_t *wqkv_t, *wo_t, *w1_t, *w2_t;
        if (hoist) {
            wqkv_t = wqkv_all + (size_t)l * 1024 * 3072;
            wo_t = wo_all + (size_t)l * 1024 * 1024;
            w1_t = w1_all + (size_t)l * 1024 * 4096;
            w2_t = w2_all + (size_t)l * 4096 * 1024;
        } else {
            wqkv_t = wqkv_1; wo_t = wo_1; w1_t = w12_1; w2_t = w12_1;
            transpose_kernel<<<dim3(48, 16, 1), 256, 0, stream>>>(
                w_qkv + (size_t)l * 1024 * 3072, wqkv_t, 1024, 3072);
            transpose_kernel<<<dim3(16, 16, 1), 256, 0, stream>>>(
                w_out + (size_t)l * 1024 * 1024, wo_t, 1024, 1024);
        }
        ln_kernel<<<2048, 256, 0, stream>>>(res, ln1_s + l * 1024, ln1_b + l * 1024, h);
        gemm_bt_kernel<0, 2><<<dim3(48, 32), 256, 0, stream>>>(
            h, wqkv_t, nullptr, nullptr, nullptr, qb, kb, vtb, 1024, 3072);
        attn_kernel<<<dim3(16, 32), 256, 0, stream>>>(qb, kb, vtb, ob);
        gemm_bt_kernel<1, 3><<<dim3(16, 32), 256, 0, stream>>>(
            ob, wo_t, b_out + l * 1024, res, nullptr, nullptr, nullptr, nullptr,
            1024, 1024);
        if (!hoist)
            transpose_kernel<<<dim3(64, 16, 1), 256, 0, stream>>>(
                w1 + (size_t)l * 1024 * 4096, w1_t, 1024, 4096);
        ln_kernel<<<2048, 256, 0, stream>>>(res, ln2_s + l * 1024, ln2_b + l * 1024, h);
        gemm_bt_kernel<2, 2><<<dim3(64, 32), 256, 0, stream>>>(
            h, w1_t, b1 + l * 4096, nullptr, ub, nullptr, nullptr, nullptr,
            1024, 4096);
        if (!hoist)
            transpose_kernel<<<dim3(16, 64, 1), 256, 0, stream>>>(
                w2 + (size_t)l * 4096 * 1024, w2_t, 4096, 1024);
        gemm_bt_kernel<1, 3><<<dim3(16, 32), 256, 0, stream>>>(
            ub, w2_t, b2 + l * 1024, res, nullptr, nullptr, nullptr, nullptr,
            4096, 1024);
    }
}